// Round 6
// baseline (9757.027 us; speedup 1.0000x reference)
//
#include <hip/hip_runtime.h>
#include <hip/hip_bf16.h>

#define B_ 64
#define T_ 2048
#define I_ 256
#define H_ 512
#define O_ 256
#define GBC 2            // batch groups
#define GHC 32           // hidden-slice groups
#define MB (B_/GBC)      // 32 rows per WG
#define HS (H_/GHC)      // 16 hidden units per WG
#define NC (4*HS)        // 64 gate cols per WG
#define KK (I_+H_)       // 768 fused K (x | h)
#define GSTR 68          // gates LDS row stride (dwords, pad)

// LDS layout (bytes)
#define XSTR 528         // 512 B bf16 row + 16 pad  (132 dw = 4 mod 32)
#define XBUFB (MB*XSTR)  // 16,896 per x buffer
#define HSTR 1040        // 1024 B bf16 row + 16 pad (260 dw = 4 mod 32)
#define HOFF (2*XBUFB)   // 33,792
#define GOFF (HOFF + MB*HSTR)   // 67,072
#define LDSB (GOFF + MB*GSTR*4) // 75,776

typedef __attribute__((ext_vector_type(8))) short short8;
typedef __attribute__((ext_vector_type(4))) float f32x4;
typedef __attribute__((ext_vector_type(4))) float float4v;
typedef __attribute__((ext_vector_type(4))) int int4v;

__device__ __forceinline__ unsigned short f2bf(float f) {
  union { float f; unsigned u; } v; v.f = f;
  unsigned r = v.u + 0x7fffu + ((v.u >> 16) & 1u);   // RNE
  return (unsigned short)(r >> 16);
}
__device__ __forceinline__ unsigned asu(float f) { union { float f; unsigned u; } v; v.f = f; return v.u; }

__device__ __forceinline__ unsigned pk2(float lo, float hi) {   // v_cvt_pk_bf16_f32 (RNE)
  __hip_bfloat162 t = __float22bfloat162_rn(make_float2(lo, hi));
  union { __hip_bfloat162 b; unsigned u; } v; v.b = t; return v.u;
}
__device__ __forceinline__ short8 pack8v(float4v a, float4v b) {
  union { unsigned u[4]; short8 s; } r;
  r.u[0] = pk2(a[0], a[1]); r.u[1] = pk2(a[2], a[3]);
  r.u[2] = pk2(b[0], b[1]); r.u[3] = pk2(b[2], b[3]);
  return r.s;
}

// agent-coherent 16-B load (bypasses stale local L2; LLC-served)
__device__ __forceinline__ void ld_x4_sc1(int4v& v, const unsigned* p) {
  asm volatile("global_load_dwordx4 %0, %1, off sc1" : "=v"(v) : "v"(p) : "memory");
}
// plain 16-B load as asm so it sits in OUR vmcnt ledger (counted waits)
__device__ __forceinline__ void ld_x4f(float4v& v, const float* p) {
  asm volatile("global_load_dwordx4 %0, %1, off" : "=v"(v) : "v"(p) : "memory");
}

// ---------------- init: zero hexf[2][B_][H_] ----------------
__global__ void init_kernel(unsigned int* __restrict__ p, int n4) {
  int i = blockIdx.x * 256 + threadIdx.x;
  if (i < n4) p[i] = 0u;
}

// ---------------- weight/bias repack: Wcat[gh][c][k] bf16 ----------------
__global__ void prep_kernel(const float* __restrict__ Wx, const float* __restrict__ Wh,
                            const float* __restrict__ bias,
                            unsigned short* __restrict__ Wcat, float* __restrict__ bcat) {
  int idx = blockIdx.x * 256 + threadIdx.x;      // over [KK][2048], exact
  int k = idx >> 11;
  int gcol = idx & 2047;
  float v = (k < I_) ? Wx[k * 2048 + gcol] : Wh[(k - I_) * 2048 + gcol];
  int gate = gcol >> 9, j = gcol & 511;
  int gh = j >> 4, jj = j & 15;
  int c = (gate << 4) | jj;                      // local col = gate*16+jj
  Wcat[((size_t)(gh * NC + c) * KK) + k] = f2bf(v);
  if (k == 0) bcat[gh * NC + c] = bias[gcol];
}

// ---------------- persistent LSTM recurrence ----------------
__global__ __launch_bounds__(512, 1) void lstm_kernel(
    const float* __restrict__ x,
    const unsigned short* __restrict__ Wcat,
    const float* __restrict__ bcat,
    unsigned* hexf,                      // [2][B_][H_] tagged f32 (LLC traffic)
    float* __restrict__ hout, float* __restrict__ cout)
{
  __shared__ __align__(16) char L[LDSB];
  float* gates = reinterpret_cast<float*>(&L[GOFF]);

  const int tid = threadIdx.x;
  const int wg = blockIdx.x;
  // XCD-aware: wg%8 in {0..3} -> batch group 0, {4..7} -> group 1
  const int gb = (wg >> 2) & 1;
  const int gh = ((wg >> 3) << 2) | (wg & 3);
  const int bbase = gb * MB;
  const int hbase = gh * HS;
  const int lane = tid & 63, wid = tid >> 6;
  const int mt = wid >> 2, nt = wid & 3;           // 2 M-tiles x 4 N-tiles = 8 waves

  // --- W fragments: pinned into AGPRs (24 x 4 regs = 96)
  short8 wfrag[24];
  {
    const int col = nt * 16 + (lane & 15);
    const short8* wsrc = reinterpret_cast<const short8*>(
        Wcat + (size_t)(gh * NC + col) * KK + ((lane >> 4) * 8));
#pragma unroll
    for (int kk = 0; kk < 24; ++kk) wfrag[kk] = wsrc[kk * 4];
#pragma unroll
    for (int kk = 0; kk < 24; ++kk) asm volatile("" : "+a"(wfrag[kk]));
  }
  const int c15 = lane & 15;
  const float bias_l = bcat[gh * NC + nt * 16 + c15];

  const int l31 = lane & 31, lhi = lane >> 5;
  const int crow = tid >> 4, cjj = tid & 15;       // nonlin mapping (1 cell/thread)
  const int arow = mt * 16 + c15;                  // GEMM A row
  const int afr = (lane >> 4) * 16;                // GEMM A frag byte offset

  float creg = 0.f;
  float4v xr[4];
  int bud = 1 << 20;

  // ---- prologue: stage x[t=0] -> xbuf[1] (C++ loads, one-time); then issue
  //      x[t=1] loads via asm (they become the "4 oldest" for step 1's vmcnt(8))
#pragma unroll
  for (int p = 0; p < 2; ++p) {
    const int xrow = 4 * wid + 2 * p + lhi;
    const float* xp = x + ((size_t)(bbase + xrow) * T_ + 0) * I_ + 8 * l31;
    float4v a = *reinterpret_cast<const float4v*>(xp);
    float4v b = *reinterpret_cast<const float4v*>(xp + 4);
    *reinterpret_cast<short8*>(&L[XBUFB + xrow * XSTR + 16 * l31]) = pack8v(a, b);
  }
#pragma unroll
  for (int p = 0; p < 2; ++p) {
    const int xrow = 4 * wid + 2 * p + lhi;
    const float* xp = x + ((size_t)(bbase + xrow) * T_ + 1) * I_ + 8 * l31;
    ld_x4f(xr[2 * p], xp);
    ld_x4f(xr[2 * p + 1], xp + 4);
  }

  for (int s = 1; s <= T_; ++s) {
    const int bprev = (s - 1) & 1, bcur = s & 1;
    const unsigned tagexp = (unsigned)((s - 1) & 3);

    // ---- P0a: issue the 8 h chunk loads FIRST (oldest in the vmcnt ledger)
    int4v hv[8];
    const unsigned* hb = hexf + (size_t)bprev * B_ * H_ + (size_t)bbase * H_ + 8 * lane;
#pragma unroll
    for (int i = 0; i < 8; ++i)
      ld_x4_sc1(hv[i], hb + (size_t)(8 * (i >> 1) + wid) * H_ + 4 * (i & 1));

    // ---- P0b: drain ONLY the previous step's 4 x loads (oldest), xr now valid
    asm volatile("s_waitcnt vmcnt(8)" ::: "memory");
    __builtin_amdgcn_sched_barrier(0);

    // ---- P0c: stage xr (= x[t=s]) into xbuf[(s+1)&1] (consumed next step)
    if (s < T_) {
#pragma unroll
      for (int p = 0; p < 2; ++p) {
        const int xrow = 4 * wid + 2 * p + lhi;
        *reinterpret_cast<short8*>(&L[((s + 1) & 1) * XBUFB + xrow * XSTR + 16 * l31]) =
            pack8v(xr[2 * p], xr[2 * p + 1]);
      }
    }

    // ---- P0d: issue x loads for t=s+1 (newest; fly across the poll + barriers)
    if (s + 1 < T_) {
#pragma unroll
      for (int p = 0; p < 2; ++p) {
        const int xrow = 4 * wid + 2 * p + lhi;
        const float* xp = x + ((size_t)(bbase + xrow) * T_ + (s + 1)) * I_ + 8 * l31;
        ld_x4f(xr[2 * p], xp);
        ld_x4f(xr[2 * p + 1], xp + 4);
      }
    }

    // ---- P1: x-part GEMM (K=0..255) on xbuf[s&1] — overlaps h flight
    f32x4 acc = {bias_l, bias_l, bias_l, bias_l};
    {
      const char* xb = &L[(s & 1) * XBUFB + arow * XSTR + afr];
#pragma unroll
      for (int kk = 0; kk < 8; ++kk) {
        short8 a = *reinterpret_cast<const short8*>(xb + kk * 64);
        acc = __builtin_amdgcn_mfma_f32_16x16x32_bf16(a, wfrag[kk], acc, 0, 0, 0);
      }
    }

    // ---- P2: poll. First wait drains exactly the 8 h loads (vmcnt(4) leaves
    //      the 4 newest = this step's x loads in flight); retries drain all.
    if (s + 1 < T_) { asm volatile("s_waitcnt vmcnt(4)" ::: "memory"); }
    else            { asm volatile("s_waitcnt vmcnt(0)" ::: "memory"); }
    __builtin_amdgcn_sched_barrier(0);
    while (true) {
      int ok = 1;
#pragma unroll
      for (int i = 0; i < 8; ++i)
#pragma unroll
        for (int j = 0; j < 4; ++j)
          ok &= (int)(((unsigned)hv[i][j] & 3u) == tagexp);
      if (__all(ok) || --bud < 0) break;
      __builtin_amdgcn_s_sleep(1);
#pragma unroll
      for (int i = 0; i < 8; ++i)
        ld_x4_sc1(hv[i], hb + (size_t)(8 * (i >> 1) + wid) * H_ + 4 * (i & 1));
      asm volatile("s_waitcnt vmcnt(0)" ::: "memory");
      __builtin_amdgcn_sched_barrier(0);
    }

    // ---- P3: stage h -> LDS bf16, lane-contiguous 16 B (conflict-free)
#pragma unroll
    for (int p = 0; p < 4; ++p) {
      union { int4v i; float4v f; } u0, u1;
      u0.i = hv[2 * p]; u1.i = hv[2 * p + 1];
      *reinterpret_cast<short8*>(&L[HOFF + (8 * p + wid) * HSTR + 16 * lane]) =
          pack8v(u0.f, u1.f);
    }
    __syncthreads();   // B1

    // ---- P4: h-part GEMM (K=256..767) + gates write
    {
      const char* hbq = &L[HOFF + arow * HSTR + afr];
#pragma unroll
      for (int kk = 0; kk < 16; ++kk) {
        short8 a = *reinterpret_cast<const short8*>(hbq + kk * 64);
        acc = __builtin_amdgcn_mfma_f32_16x16x32_bf16(a, wfrag[8 + kk], acc, 0, 0, 0);
      }
      const int col = nt * 16 + c15;
      const int r0 = mt * 16 + ((lane >> 4) << 2);
      gates[(r0 + 0) * GSTR + col] = acc[0];
      gates[(r0 + 1) * GSTR + col] = acc[1];
      gates[(r0 + 2) * GSTR + col] = acc[2];
      gates[(r0 + 3) * GSTR + col] = acc[3];
    }
    __syncthreads();   // B2

    // ---- P5: nonlinearities + cell update + tagged h publish
    {
      const float* grow = &gates[crow * GSTR];
      float ig = grow[cjj], fg = grow[16 + cjj], gg = grow[32 + cjj], og = grow[48 + cjj];
      float i_ = 1.f / (1.f + __expf(-ig));
      float f_ = 1.f / (1.f + __expf(-fg));
      float g_ = 1.f - 2.f / (__expf(2.f * gg) + 1.f);   // tanh
      float o_ = 1.f / (1.f + __expf(-og));
      creg = f_ * creg + i_ * g_;
      float hvf = o_ * (1.f - 2.f / (__expf(2.f * creg) + 1.f));
      __hip_atomic_store(
          hexf + (size_t)bcur * B_ * H_ + (size_t)(bbase + crow) * H_ + hbase + cjj,
          (asu(hvf) & ~3u) | (unsigned)(s & 3),
          __ATOMIC_RELAXED, __HIP_MEMORY_SCOPE_AGENT);
      if (s == T_) {
        hout[(bbase + crow) * H_ + hbase + cjj] = hvf;
        cout[(bbase + crow) * H_ + hbase + cjj] = creg;
      }
    }
    // no trailing barrier: next-step LDS writes hit regions protected by B1/B2
  }
}

// ---------------- final FC: y = h_T @ fc_w^T + fc_b ----------------
__global__ void fc_kernel(const float* __restrict__ hT, const float* __restrict__ fcw,
                          const float* __restrict__ fcb, float* __restrict__ y) {
  __shared__ float hr[H_];
  const int b = blockIdx.x, o = threadIdx.x;
  hr[o] = hT[b * H_ + o];
  hr[o + 256] = hT[b * H_ + 256 + o];
  __syncthreads();
  const float4v* w = reinterpret_cast<const float4v*>(fcw + (size_t)o * H_);
  const float4v* h4 = reinterpret_cast<const float4v*>(hr);
  float s0 = 0.f, s1 = 0.f, s2 = 0.f, s3 = 0.f;
#pragma unroll 8
  for (int k = 0; k < H_ / 4; ++k) {
    float4v wv = w[k], hv = h4[k];
    s0 += wv[0] * hv[0]; s1 += wv[1] * hv[1];
    s2 += wv[2] * hv[2]; s3 += wv[3] * hv[3];
  }
  y[b * O_ + o] = s0 + s1 + s2 + s3 + fcb[o];
}

extern "C" void kernel_launch(void* const* d_in, const int* in_sizes, int n_in,
                              void* d_out, int out_size, void* d_ws, size_t ws_size,
                              hipStream_t stream) {
  const float* x    = (const float*)d_in[0];
  const float* Wx   = (const float*)d_in[1];
  const float* Wh   = (const float*)d_in[2];
  const float* bias = (const float*)d_in[3];
  const float* fcw  = (const float*)d_in[4];
  const float* fcb  = (const float*)d_in[5];
  float* out = (float*)d_out;                 // [y 16384 | h 32768 | c 32768]

  char* ws = (char*)d_ws;
  unsigned short* Wcat = (unsigned short*)ws;                       // 3,145,728 B
  float* bcat          = (float*)(ws + 3145728);                    //     8,192 B
  unsigned* hexf       = (unsigned*)(ws + 3145728 + 8192);          //   262,144 B

  // zero hexf (both buffers; tag 0 == valid h_0) — every call (buffers persist!)
  init_kernel<<<dim3(256), dim3(256), 0, stream>>>((unsigned int*)hexf, 65536);
  // repack weights to bf16 [32][64][768] + bias [32][64]
  prep_kernel<<<dim3((KK * 2048) / 256), dim3(256), 0, stream>>>(Wx, Wh, bias, Wcat, bcat);
  // persistent recurrence: 64 WGs (2 batch groups x 32 hidden slices), 512 threads
  lstm_kernel<<<dim3(GBC * GHC), dim3(512), 0, stream>>>(
      x, Wcat, bcat, hexf, out + 16384, out + 16384 + 32768);
  // final projection
  fc_kernel<<<dim3(B_), dim3(256), 0, stream>>>(out + 16384, fcw, fcb, out);
}